// Round 1
// 570.640 us; speedup vs baseline: 1.1318x; 1.1318x over previous
//
#include <hip/hip_runtime.h>
#include <hip/hip_bf16.h>

typedef __hip_bfloat16 bf16;
typedef __attribute__((ext_vector_type(8))) short short8;
typedef __attribute__((ext_vector_type(4))) float floatx4;

#define NPIX  131072
#define BATCH 2
#define HH    256
#define WW    256
#define CDIM  96
#define C3    288
#define HEADS 2
#define CH    48
#define HIDN  255
#define HWSZ  65536
#define EPSV  1e-5f

__device__ __forceinline__ float b2f(bf16 v) { return __bfloat162float(v); }
__device__ __forceinline__ bf16  f2b(float v) { return __float2bfloat16(v); }
__device__ __forceinline__ short f2bs(float v) { bf16 h = __float2bfloat16(v); return *reinterpret_cast<short*>(&h); }
__device__ __forceinline__ float lo16(unsigned u) { return __uint_as_float(u << 16); }
__device__ __forceinline__ float hi16(unsigned u) { return __uint_as_float(u & 0xffff0000u); }

// ======== One-shot weight transpose to k-major bf16 ========
// WQ  [288][96]  <- qkv_w[96][288]
// WF1 [256][96]  <- ffn_in_w[96][510] cols 0..254   (row 255 zeros)
// WF2 [256][96]  <- ffn_in_w[96][510] cols 255..509 (row 255 zeros)
// WO  [96][256]  <- ffn_out_w[255][96]              (k=255 zeros)
__global__ __launch_bounds__(256) void prep_wt(
    const float* __restrict__ qkv_w, const float* __restrict__ ffn_in_w,
    const float* __restrict__ ffn_out_w,
    bf16* __restrict__ WQ, bf16* __restrict__ WF1, bf16* __restrict__ WF2,
    bf16* __restrict__ WO)
{
  int gid = blockIdx.x * 256 + threadIdx.x;
  if (gid < 27648) {                       // 288*96
    int n = gid / 96, k = gid - n * 96;
    WQ[gid] = f2b(qkv_w[k * C3 + n]);
  } else if (gid < 27648 + 24576) {        // 256*96
    int g = gid - 27648;
    int n = g / 96, k = g - n * 96;
    WF1[g] = f2b(n < HIDN ? ffn_in_w[k * (2 * HIDN) + n] : 0.f);
  } else if (gid < 27648 + 49152) {
    int g = gid - 27648 - 24576;
    int n = g / 96, k = g - n * 96;
    WF2[g] = f2b(n < HIDN ? ffn_in_w[k * (2 * HIDN) + HIDN + n] : 0.f);
  } else {                                 // 96*256
    int g = gid - 27648 - 49152;
    int n = g / 256, k = g - n * 256;
    WO[g] = f2b(k < HIDN ? ffn_out_w[k * CDIM + n] : 0.f);
  }
}

// ======== Generic MFMA GEMM, B direct from global (k-major bf16 Wt) ========
// out[M, BN] = A[M, KT bf16, lda] * Wt[BN][KT]^T (+res). 1-D grid over rows.
template<int BM, int BN, int KT, bool ADD_RES, bool OUT_BF16>
__global__ __launch_bounds__(256, 2) void mfma_gemm(
    const bf16* __restrict__ A, int lda,
    const bf16* __restrict__ Wt,
    void* __restrict__ outp, int ldo,
    const float* __restrict__ res, int ldr)
{
  constexpr int NK  = KT / 32;
  constexpr int NCT = BN / 16;
  constexpr int RT  = BM / 64;
  const int tid  = threadIdx.x;
  const long bm  = (long)blockIdx.x * BM;
  const int lane = tid & 63;
  const int wv   = tid >> 6;
  const int m15  = lane & 15;
  const int quad = lane >> 4;

  short8 areg[RT][NK];
  #pragma unroll
  for (int rt = 0; rt < RT; ++rt) {
    const bf16* ap = A + (bm + wv * (BM / 4) + rt * 16 + m15) * lda + quad * 8;
    #pragma unroll
    for (int kk = 0; kk < NK; ++kk)
      areg[rt][kk] = *reinterpret_cast<const short8*>(ap + kk * 32);
  }

  floatx4 acc[RT][NCT];
  #pragma unroll
  for (int rt = 0; rt < RT; ++rt)
    #pragma unroll
    for (int ct = 0; ct < NCT; ++ct)
      acc[rt][ct] = (floatx4){0.f, 0.f, 0.f, 0.f};

  const bf16* wp = Wt + m15 * KT + quad * 8;
  #pragma unroll
  for (int kk = 0; kk < NK; ++kk)
    #pragma unroll
    for (int ct = 0; ct < NCT; ++ct) {
      short8 b = *reinterpret_cast<const short8*>(wp + ct * 16 * KT + kk * 32);
      #pragma unroll
      for (int rt = 0; rt < RT; ++rt)
        acc[rt][ct] = __builtin_amdgcn_mfma_f32_16x16x32_bf16(areg[rt][kk], b, acc[rt][ct], 0, 0, 0);
    }

  #pragma unroll
  for (int rt = 0; rt < RT; ++rt)
    #pragma unroll
    for (int ct = 0; ct < NCT; ++ct) {
      int col = ct * 16 + m15;
      #pragma unroll
      for (int r = 0; r < 4; ++r) {
        long row = bm + wv * (BM / 4) + rt * 16 + quad * 4 + r;
        float v = acc[rt][ct][r];
        if (ADD_RES) v += res[row * ldr + col];
        if (OUT_BF16) ((bf16*)outp)[row * ldo + col] = f2b(v);
        else          ((float*)outp)[row * ldo + col] = v;
      }
    }
}

// ======== qkv GEMM with fused LayerNorm on A, full 288-col output/block ========
__global__ __launch_bounds__(256, 2) void mfma_gemm_lnA(
    const float* __restrict__ X, const float* __restrict__ gam, const float* __restrict__ bet,
    const bf16* __restrict__ Wt,   // [288][96]
    bf16* __restrict__ outp)
{
  const int tid  = threadIdx.x;
  const long bm  = (long)blockIdx.x * 128;
  const int lane = tid & 63;
  const int wv   = tid >> 6;
  const int m15  = lane & 15;
  const int quad = lane >> 4;

  // load x rows (fp32), all 3 k-slices
  float xv[2][24];
  #pragma unroll
  for (int rt = 0; rt < 2; ++rt) {
    const float* xp = X + (bm + wv * 32 + rt * 16 + m15) * CDIM + quad * 8;
    #pragma unroll
    for (int kk = 0; kk < 3; ++kk) {
      float4 t0 = *reinterpret_cast<const float4*>(xp + kk * 32);
      float4 t1 = *reinterpret_cast<const float4*>(xp + kk * 32 + 4);
      xv[rt][kk * 8 + 0] = t0.x; xv[rt][kk * 8 + 1] = t0.y; xv[rt][kk * 8 + 2] = t0.z; xv[rt][kk * 8 + 3] = t0.w;
      xv[rt][kk * 8 + 4] = t1.x; xv[rt][kk * 8 + 5] = t1.y; xv[rt][kk * 8 + 6] = t1.z; xv[rt][kk * 8 + 7] = t1.w;
    }
  }
  float gv[24], bv[24];
  #pragma unroll
  for (int kk = 0; kk < 3; ++kk) {
    float4 g0 = *reinterpret_cast<const float4*>(gam + kk * 32 + quad * 8);
    float4 g1 = *reinterpret_cast<const float4*>(gam + kk * 32 + quad * 8 + 4);
    float4 b0 = *reinterpret_cast<const float4*>(bet + kk * 32 + quad * 8);
    float4 b1 = *reinterpret_cast<const float4*>(bet + kk * 32 + quad * 8 + 4);
    gv[kk * 8 + 0] = g0.x; gv[kk * 8 + 1] = g0.y; gv[kk * 8 + 2] = g0.z; gv[kk * 8 + 3] = g0.w;
    gv[kk * 8 + 4] = g1.x; gv[kk * 8 + 5] = g1.y; gv[kk * 8 + 6] = g1.z; gv[kk * 8 + 7] = g1.w;
    bv[kk * 8 + 0] = b0.x; bv[kk * 8 + 1] = b0.y; bv[kk * 8 + 2] = b0.z; bv[kk * 8 + 3] = b0.w;
    bv[kk * 8 + 4] = b1.x; bv[kk * 8 + 5] = b1.y; bv[kk * 8 + 6] = b1.z; bv[kk * 8 + 7] = b1.w;
  }

  short8 areg[2][3];
  #pragma unroll
  for (int rt = 0; rt < 2; ++rt) {
    float s = 0.f, sq = 0.f;
    #pragma unroll
    for (int e = 0; e < 24; ++e) { s += xv[rt][e]; sq += xv[rt][e] * xv[rt][e]; }
    s  += __shfl_xor(s, 16);  s  += __shfl_xor(s, 32);
    sq += __shfl_xor(sq, 16); sq += __shfl_xor(sq, 32);
    float mean = s * (1.f / 96.f);
    float var  = sq * (1.f / 96.f) - mean * mean;
    float rstd = rsqrtf(var + EPSV);
    #pragma unroll
    for (int kk = 0; kk < 3; ++kk)
      #pragma unroll
      for (int j = 0; j < 8; ++j)
        areg[rt][kk][j] = f2bs((xv[rt][kk * 8 + j] - mean) * rstd * gv[kk * 8 + j] + bv[kk * 8 + j]);
  }

  floatx4 acc[2][18];
  #pragma unroll
  for (int rt = 0; rt < 2; ++rt)
    #pragma unroll
    for (int ct = 0; ct < 18; ++ct)
      acc[rt][ct] = (floatx4){0.f, 0.f, 0.f, 0.f};

  const bf16* wp = Wt + m15 * 96 + quad * 8;
  #pragma unroll
  for (int kk = 0; kk < 3; ++kk)
    #pragma unroll
    for (int ct = 0; ct < 18; ++ct) {
      short8 b = *reinterpret_cast<const short8*>(wp + ct * 16 * 96 + kk * 32);
      #pragma unroll
      for (int rt = 0; rt < 2; ++rt)
        acc[rt][ct] = __builtin_amdgcn_mfma_f32_16x16x32_bf16(areg[rt][kk], b, acc[rt][ct], 0, 0, 0);
    }

  #pragma unroll
  for (int rt = 0; rt < 2; ++rt)
    #pragma unroll
    for (int ct = 0; ct < 18; ++ct) {
      int col = ct * 16 + m15;
      #pragma unroll
      for (int r = 0; r < 4; ++r) {
        long row = bm + wv * 32 + rt * 16 + quad * 4 + r;
        outp[row * C3 + col] = f2b(acc[rt][ct][r]);
      }
    }
}

// ======== attn-out GEMM (v @ M_b^T) + residual + fused LayerNorm2 epilogue ========
// Mt: per-batch [96][96] bf16, k-major. out = x + v@M (fp32), y2 = LN(out) (bf16).
__global__ __launch_bounds__(256, 2) void mfma_gemm_attn(
    const bf16* __restrict__ A, const bf16* __restrict__ Mt,
    const float* __restrict__ res, const float* __restrict__ gam, const float* __restrict__ bet,
    float* __restrict__ outp, bf16* __restrict__ y2)
{
  const int tid  = threadIdx.x;
  const long bm  = (long)blockIdx.x * 128;
  const int lane = tid & 63;
  const int wv   = tid >> 6;
  const int m15  = lane & 15;
  const int quad = lane >> 4;

  short8 areg[2][3];
  #pragma unroll
  for (int rt = 0; rt < 2; ++rt) {
    const bf16* ap = A + (bm + wv * 32 + rt * 16 + m15) * C3 + quad * 8;
    #pragma unroll
    for (int kk = 0; kk < 3; ++kk)
      areg[rt][kk] = *reinterpret_cast<const short8*>(ap + kk * 32);
  }

  floatx4 acc[2][6];
  #pragma unroll
  for (int rt = 0; rt < 2; ++rt)
    #pragma unroll
    for (int ct = 0; ct < 6; ++ct)
      acc[rt][ct] = (floatx4){0.f, 0.f, 0.f, 0.f};

  const bf16* mp = Mt + (bm >> 16) * (CDIM * CDIM) + m15 * 96 + quad * 8;
  #pragma unroll
  for (int kk = 0; kk < 3; ++kk)
    #pragma unroll
    for (int ct = 0; ct < 6; ++ct) {
      short8 b = *reinterpret_cast<const short8*>(mp + ct * 16 * 96 + kk * 32);
      #pragma unroll
      for (int rt = 0; rt < 2; ++rt)
        acc[rt][ct] = __builtin_amdgcn_mfma_f32_16x16x32_bf16(areg[rt][kk], b, acc[rt][ct], 0, 0, 0);
    }

  float gv[6], bv[6];
  #pragma unroll
  for (int ct = 0; ct < 6; ++ct) { gv[ct] = gam[ct * 16 + m15]; bv[ct] = bet[ct * 16 + m15]; }

  #pragma unroll
  for (int rt = 0; rt < 2; ++rt)
    #pragma unroll
    for (int r = 0; r < 4; ++r) {
      long row = bm + wv * 32 + rt * 16 + quad * 4 + r;
      float v[6];
      float s = 0.f, sq = 0.f;
      #pragma unroll
      for (int ct = 0; ct < 6; ++ct) {
        v[ct] = acc[rt][ct][r] + res[row * CDIM + ct * 16 + m15];
        s += v[ct]; sq += v[ct] * v[ct];
      }
      #pragma unroll
      for (int off = 8; off; off >>= 1) { s += __shfl_xor(s, off); sq += __shfl_xor(sq, off); }
      float mean = s * (1.f / 96.f);
      float var  = sq * (1.f / 96.f) - mean * mean;
      float rstd = rsqrtf(var + EPSV);
      #pragma unroll
      for (int ct = 0; ct < 6; ++ct) {
        int col = ct * 16 + m15;
        outp[row * CDIM + col] = v[ct];
        y2[row * CDIM + col] = f2b((v[ct] - mean) * rstd * gv[ct] + bv[ct]);
      }
    }
}

// ======== Spatially-tiled depthwise 3x3 conv, vectorized 8-ch I/O ========
template<int LDC, int TC, int MODE>
__global__ __launch_bounds__(256) void dwconv_tiled(
    const bf16* __restrict__ in, const float* __restrict__ kw, int kws, int cmax,
    bf16* __restrict__ out, int ldo)
{
  constexpr int VPP = TC / 8;
  __shared__ uint4 sm[VPP][18 * 18];
  const int tid = threadIdx.x;
  const int tx0 = blockIdx.x * 16;
  const int ty0 = (blockIdx.y & 15) * 16;
  const int b   = blockIdx.y >> 4;
  const int c0  = blockIdx.z * TC;
  const long bbase = (long)b * HWSZ;

  for (int f = tid; f < 18 * 18 * VPP; f += 256) {
    int pix = f / VPP;
    int v   = f - pix * VPP;
    int row = pix / 18, px = pix - row * 18;
    int y = ty0 + row - 1, x = tx0 + px - 1;
    uint4 u = make_uint4(0u, 0u, 0u, 0u);
    if ((unsigned)y < (unsigned)HH && (unsigned)x < (unsigned)WW)
      u = *reinterpret_cast<const uint4*>(in + (bbase + (long)y * WW + x) * LDC + c0 + v * 8);
    sm[v][pix] = u;
  }
  __syncthreads();

  const int x   = tid & 15;
  const int yg  = (tid >> 4) & 3;
  const int chl = tid >> 6;
  for (int cg = chl; cg < VPP; cg += 4) {
    const int cb = c0 + cg * 8;
    float wgt[9][8];
    #pragma unroll
    for (int t = 0; t < 9; ++t)
      #pragma unroll
      for (int j = 0; j < 8; ++j)
        wgt[t][j] = (cb + j < cmax) ? kw[t * kws + cb + j] : 0.f;

    #pragma unroll
    for (int yy = 0; yy < 4; ++yy) {
      const int ry = yg * 4 + yy;
      float acc[8] = {0.f, 0.f, 0.f, 0.f, 0.f, 0.f, 0.f, 0.f};
      #pragma unroll
      for (int dy = 0; dy < 3; ++dy)
        #pragma unroll
        for (int dx = 0; dx < 3; ++dx) {
          uint4 u = sm[cg][(ry + dy) * 18 + x + dx];
          const float* wt = wgt[dy * 3 + dx];
          acc[0] += lo16(u.x) * wt[0]; acc[1] += hi16(u.x) * wt[1];
          acc[2] += lo16(u.y) * wt[2]; acc[3] += hi16(u.y) * wt[3];
          acc[4] += lo16(u.z) * wt[4]; acc[5] += hi16(u.z) * wt[5];
          acc[6] += lo16(u.w) * wt[6]; acc[7] += hi16(u.w) * wt[7];
        }
      long po = bbase + (long)(ty0 + yg * 4 + yy) * WW + tx0 + x;
      bf16* op = out + po * ldo + cb;
      __align__(16) bf16 ov[8];
      if (MODE == 0) {
        #pragma unroll
        for (int j = 0; j < 8; ++j) ov[j] = f2b(acc[j]);
      } else if (MODE == 1) {
        #pragma unroll
        for (int j = 0; j < 8; ++j)
          ov[j] = f2b(0.5f * acc[j] * (1.f + erff(acc[j] * 0.70710678118654752440f)));
      } else {
        uint4 old = *reinterpret_cast<const uint4*>(op);
        ov[0] = f2b(lo16(old.x) * acc[0]); ov[1] = f2b(hi16(old.x) * acc[1]);
        ov[2] = f2b(lo16(old.y) * acc[2]); ov[3] = f2b(hi16(old.y) * acc[3]);
        ov[4] = f2b(lo16(old.z) * acc[4]); ov[5] = f2b(hi16(old.z) * acc[5]);
        ov[6] = f2b(lo16(old.w) * acc[6]); ov[7] = f2b(hi16(old.w) * acc[7]);
      }
      *reinterpret_cast<uint4*>(op) = *reinterpret_cast<const uint4*>(ov);
    }
  }
}

// ======== MFMA Gram + fused q/k L2 norms ========
__global__ __launch_bounds__(256) void gram_kernel(const bf16* __restrict__ qkv,
    float* __restrict__ G, float* __restrict__ nq, float* __restrict__ nk)
{
  constexpr int SP = 264;
  __shared__ __align__(16) char raw[2 * CH * SP * 2];   // 50688 B
  short* qs = (short*)raw;              // [48][SP]
  short* ks = qs + CH * SP;
  const int tid  = threadIdx.x;
  const int bh   = blockIdx.y;
  const int b    = bh >> 1, head = bh & 1;
  const long row0 = (long)b * HWSZ + (long)blockIdx.x * 256;
  const int lane = tid & 63;
  const int wv   = tid >> 6;
  const int m15  = lane & 15;
  const int quad = lane >> 4;

  {
    const short* src = (const short*)(qkv + (row0 + tid) * C3 + head * CH);
    #pragma unroll
    for (int v = 0; v < 6; ++v) {
      short8 q8 = *reinterpret_cast<const short8*>(src + v * 8);
      short8 k8 = *reinterpret_cast<const short8*>(src + CDIM + v * 8);
      #pragma unroll
      for (int j = 0; j < 8; ++j) {
        qs[(v * 8 + j) * SP + tid] = q8[j];
        ks[(v * 8 + j) * SP + tid] = k8[j];
      }
    }
  }
  __syncthreads();

  floatx4 acc[3][3], accq[3], acck[3];
  #pragma unroll
  for (int i = 0; i < 3; ++i) {
    accq[i] = (floatx4){0.f, 0.f, 0.f, 0.f};
    acck[i] = (floatx4){0.f, 0.f, 0.f, 0.f};
    #pragma unroll
    for (int j = 0; j < 3; ++j) acc[i][j] = (floatx4){0.f, 0.f, 0.f, 0.f};
  }

  #pragma unroll
  for (int kk = 0; kk < 2; ++kk) {
    const int s_off = wv * 64 + kk * 32 + quad * 8;
    short8 aq[3], bk[3];
    #pragma unroll
    for (int i = 0; i < 3; ++i) {
      aq[i] = *reinterpret_cast<const short8*>(&qs[(i * 16 + m15) * SP + s_off]);
      bk[i] = *reinterpret_cast<const short8*>(&ks[(i * 16 + m15) * SP + s_off]);
    }
    #pragma unroll
    for (int i = 0; i < 3; ++i) {
      accq[i] = __builtin_amdgcn_mfma_f32_16x16x32_bf16(aq[i], aq[i], accq[i], 0, 0, 0);
      acck[i] = __builtin_amdgcn_mfma_f32_16x16x32_bf16(bk[i], bk[i], acck[i], 0, 0, 0);
      #pragma unroll
      for (int j = 0; j < 3; ++j)
        acc[i][j] = __builtin_amdgcn_mfma_f32_16x16x32_bf16(aq[i], bk[j], acc[i][j], 0, 0, 0);
    }
  }

  __syncthreads();
  float* gsum = (float*)raw;            // 2304 floats
  float* nqs  = gsum + 2304;            // 48
  float* nks  = nqs + 48;               // 48
  for (int f = tid; f < 2304 + 96; f += 256) gsum[f] = 0.f;
  __syncthreads();
  const int c_lo = quad * 4;
  #pragma unroll
  for (int i = 0; i < 3; ++i)
    #pragma unroll
    for (int j = 0; j < 3; ++j)
      #pragma unroll
      for (int r = 0; r < 4; ++r)
        atomicAdd(&gsum[(i * 16 + c_lo + r) * CH + j * 16 + m15], acc[i][j][r]);
  if (m15 >= c_lo && m15 < c_lo + 4) {
    const int r = m15 - c_lo;
    #pragma unroll
    for (int i = 0; i < 3; ++i) {
      atomicAdd(&nqs[i * 16 + m15], accq[i][r]);
      atomicAdd(&nks[i * 16 + m15], acck[i][r]);
    }
  }
  __syncthreads();
  float* Gp = G + (long)bh * CH * CH;
  for (int f = tid; f < CH * CH; f += 256) atomicAdd(&Gp[f], gsum[f]);
  if (tid < CH)            atomicAdd(&nq[b * CDIM + head * CH + tid], nqs[tid]);
  else if (tid < 2 * CH)   atomicAdd(&nk[b * CDIM + head * CH + tid - CH], nks[tid - CH]);
}

// ---------------- softmax over d of G/(|q||k|)*temp ----------------
__global__ __launch_bounds__(64) void softmax_kernel(const float* __restrict__ G,
    const float* __restrict__ nq, const float* __restrict__ nk,
    const float* __restrict__ temp, float* __restrict__ attn)
{
  int r = blockIdx.x;               // 0..191 = (b*2+head)*48 + c
  int lane = threadIdx.x;
  int bh = r / CH, c = r % CH;
  int b = bh >> 1, head = bh & 1;
  float t  = temp[head];
  float qn = sqrtf(nq[b * CDIM + head * CH + c]);
  float val = 0.f, v = -INFINITY;
  if (lane < CH) {
    float kn = sqrtf(nk[b * CDIM + head * CH + lane]);
    val = G[r * CH + lane] / (qn * kn) * t;
    v = val;
  }
  float m = v;
  #pragma unroll
  for (int off = 32; off; off >>= 1) m = fmaxf(m, __shfl_xor(m, off));
  float e = (lane < CH) ? expf(val - m) : 0.f;
  float s = e;
  #pragma unroll
  for (int off = 32; off; off >>= 1) s += __shfl_xor(s, off);
  if (lane < CH) attn[r * CH + lane] = e / s;
}

// ---- Mt[b][n][k] (bf16) = sum_cc attn[b,head(k)][cc][k%48] * aow[head(k)*48+cc][n] ----
__global__ __launch_bounds__(256) void attnmat_kernel(const float* __restrict__ attn,
    const float* __restrict__ aow, bf16* __restrict__ Mt)
{
  const int b  = blockIdx.x;
  const int k0 = blockIdx.y * 16;
  for (int idx = threadIdx.x; idx < 16 * 96; idx += 256) {
    int k = k0 + idx / 96, n = idx % 96;
    int h = k / CH, kk = k % CH;
    const float* ap = attn + ((b * 2 + h) * CH) * CH + kk;  // attn[bh][cc][kk], stride CH
    const float* wp = aow + (h * CH) * CDIM + n;            // aow[h*48+cc][n], stride CDIM
    float acc = 0.f;
    #pragma unroll
    for (int cc = 0; cc < CH; ++cc) acc += ap[cc * CH] * wp[cc * CDIM];
    Mt[(long)b * CDIM * CDIM + n * CDIM + k] = f2b(acc);    // transposed, k-major
  }
}

extern "C" void kernel_launch(void* const* d_in, const int* in_sizes, int n_in,
                              void* d_out, int out_size, void* d_ws, size_t ws_size,
                              hipStream_t stream)
{
  const float* x          = (const float*)d_in[0];
  const float* ln1_g      = (const float*)d_in[1];
  const float* ln1_b      = (const float*)d_in[2];
  const float* ln2_g      = (const float*)d_in[3];
  const float* ln2_b      = (const float*)d_in[4];
  const float* qkv_w      = (const float*)d_in[5];
  const float* qkv_dw     = (const float*)d_in[6];
  const float* temp       = (const float*)d_in[7];
  const float* attn_out_w = (const float*)d_in[8];
  const float* ffn_in_w   = (const float*)d_in[9];
  const float* ffn_dw     = (const float*)d_in[10];
  const float* ffn_out_w  = (const float*)d_in[11];
  float* out = (float*)d_out;

  // workspace layout (peak ~177 MB)
  char* ws = (char*)d_ws;
  size_t off = 0;
  auto alloc = [&](size_t bytes) { void* p = ws + off; off += (bytes + 255) & ~(size_t)255; return p; };
  bf16*  BA  = (bf16*)alloc((size_t)NPIX * C3 * 2);    // qkv post-dwconv; later gelu(x1)/gated
  bf16*  BB  = (bf16*)alloc((size_t)NPIX * C3 * 2);    // qkv pre-dwconv; later t1/t2
  bf16*  BC  = (bf16*)alloc((size_t)NPIX * CDIM * 2);  // LN2 output (from attn epilogue)
  float* NQ  = (float*)alloc(BATCH * CDIM * 4);
  float* NK  = (float*)alloc(BATCH * CDIM * 4);
  float* G   = (float*)alloc(BATCH * HEADS * CH * CH * 4);
  float* ATT = (float*)alloc(BATCH * HEADS * CH * CH * 4);
  bf16*  MT  = (bf16*)alloc((size_t)BATCH * CDIM * CDIM * 2); // fused attn matrices, k-major bf16
  bf16*  WQ  = (bf16*)alloc(288 * 96 * 2);
  bf16*  WF1 = (bf16*)alloc(256 * 96 * 2);
  bf16*  WF2 = (bf16*)alloc(256 * 96 * 2);
  bf16*  WO  = (bf16*)alloc(96 * 256 * 2);
  hipMemsetAsync(NQ, 0, (size_t)(768 + 768 + 36864), stream);

  // one-shot weight transposes (k-major bf16)
  prep_wt<<<396, 256, 0, stream>>>(qkv_w, ffn_in_w, ffn_out_w, WQ, WF1, WF2, WO);

  // ---- attention branch ----
  // qkv = dwconv(LN1(x) @ qkv_w)
  mfma_gemm_lnA<<<NPIX / 128, 256, 0, stream>>>(x, ln1_g, ln1_b, WQ, BB);
  dwconv_tiled<C3, 48, 0><<<dim3(16, 32, 6), 256, 0, stream>>>(BB, qkv_dw, C3, C3, BA, C3);
  gram_kernel<<<dim3(256, 4), 256, 0, stream>>>(BA, G, NQ, NK);
  softmax_kernel<<<192, 64, 0, stream>>>(G, NQ, NK, temp, ATT);
  attnmat_kernel<<<dim3(2, 6), 256, 0, stream>>>(ATT, attn_out_w, MT);
  // out = x + v @ M_b;  BC = LN2(out)
  mfma_gemm_attn<<<NPIX / 128, 256, 0, stream>>>(
      BA + 2 * CDIM, MT, x, ln2_g, ln2_b, out, BC);

  // ---- FFN branch (hidden split into two 255-col halves; col 255 pads as zeros) ----
  mfma_gemm<128, 256, 96, false, true><<<NPIX / 128, 256, 0, stream>>>(
      BC, CDIM, WF1, BB, 256, nullptr, 0);
  dwconv_tiled<256, 64, 1><<<dim3(16, 32, 4), 256, 0, stream>>>(BB, ffn_dw, 2 * HIDN, HIDN, BA, 256);
  mfma_gemm<128, 256, 96, false, true><<<NPIX / 128, 256, 0, stream>>>(
      BC, CDIM, WF2, BB, 256, nullptr, 0);
  dwconv_tiled<256, 64, 2><<<dim3(16, 32, 4), 256, 0, stream>>>(BB, ffn_dw + HIDN, 2 * HIDN, HIDN, BA, 256);
  mfma_gemm<128, 96, 256, true, false><<<NPIX / 128, 256, 0, stream>>>(
      BA, 256, WO, out, CDIM, out, CDIM);
}

// Round 2
// 534.356 us; speedup vs baseline: 1.2087x; 1.0679x over previous
//
#include <hip/hip_runtime.h>
#include <hip/hip_bf16.h>

typedef __hip_bfloat16 bf16;
typedef __attribute__((ext_vector_type(8))) short short8;
typedef __attribute__((ext_vector_type(4))) float floatx4;

#define NPIX  131072
#define BATCH 2
#define HH    256
#define WW    256
#define CDIM  96
#define C3    288
#define HEADS 2
#define CH    48
#define HIDN  255
#define HWSZ  65536
#define EPSV  1e-5f

__device__ __forceinline__ float b2f(bf16 v) { return __bfloat162float(v); }
__device__ __forceinline__ bf16  f2b(float v) { return __float2bfloat16(v); }
__device__ __forceinline__ short f2bs(float v) { bf16 h = __float2bfloat16(v); return *reinterpret_cast<short*>(&h); }
__device__ __forceinline__ float lo16(unsigned u) { return __uint_as_float(u << 16); }
__device__ __forceinline__ float hi16(unsigned u) { return __uint_as_float(u & 0xffff0000u); }

// ======== One-shot weight transpose to k-major bf16 ========
__global__ __launch_bounds__(256) void prep_wt(
    const float* __restrict__ qkv_w, const float* __restrict__ ffn_in_w,
    const float* __restrict__ ffn_out_w,
    bf16* __restrict__ WQ, bf16* __restrict__ WF1, bf16* __restrict__ WF2,
    bf16* __restrict__ WO)
{
  int gid = blockIdx.x * 256 + threadIdx.x;
  if (gid < 27648) {                       // 288*96
    int n = gid / 96, k = gid - n * 96;
    WQ[gid] = f2b(qkv_w[k * C3 + n]);
  } else if (gid < 27648 + 24576) {        // 256*96
    int g = gid - 27648;
    int n = g / 96, k = g - n * 96;
    WF1[g] = f2b(n < HIDN ? ffn_in_w[k * (2 * HIDN) + n] : 0.f);
  } else if (gid < 27648 + 49152) {
    int g = gid - 27648 - 24576;
    int n = g / 96, k = g - n * 96;
    WF2[g] = f2b(n < HIDN ? ffn_in_w[k * (2 * HIDN) + HIDN + n] : 0.f);
  } else {                                 // 96*256
    int g = gid - 27648 - 49152;
    int n = g / 256, k = g - n * 256;
    WO[g] = f2b(k < HIDN ? ffn_out_w[k * CDIM + n] : 0.f);
  }
}

// ======== Generic MFMA GEMM, B direct from global (k-major bf16 Wt) ========
template<int BM, int BN, int KT, bool ADD_RES, bool OUT_BF16>
__global__ __launch_bounds__(256, 2) void mfma_gemm(
    const bf16* __restrict__ A, int lda,
    const bf16* __restrict__ Wt,
    void* __restrict__ outp, int ldo,
    const float* __restrict__ res, int ldr)
{
  constexpr int NK  = KT / 32;
  constexpr int NCT = BN / 16;
  constexpr int RT  = BM / 64;
  const int tid  = threadIdx.x;
  const long bm  = (long)blockIdx.x * BM;
  const int lane = tid & 63;
  const int wv   = tid >> 6;
  const int m15  = lane & 15;
  const int quad = lane >> 4;

  short8 areg[RT][NK];
  #pragma unroll
  for (int rt = 0; rt < RT; ++rt) {
    const bf16* ap = A + (bm + wv * (BM / 4) + rt * 16 + m15) * lda + quad * 8;
    #pragma unroll
    for (int kk = 0; kk < NK; ++kk)
      areg[rt][kk] = *reinterpret_cast<const short8*>(ap + kk * 32);
  }

  floatx4 acc[RT][NCT];
  #pragma unroll
  for (int rt = 0; rt < RT; ++rt)
    #pragma unroll
    for (int ct = 0; ct < NCT; ++ct)
      acc[rt][ct] = (floatx4){0.f, 0.f, 0.f, 0.f};

  const bf16* wp = Wt + m15 * KT + quad * 8;
  #pragma unroll
  for (int kk = 0; kk < NK; ++kk)
    #pragma unroll
    for (int ct = 0; ct < NCT; ++ct) {
      short8 b = *reinterpret_cast<const short8*>(wp + ct * 16 * KT + kk * 32);
      #pragma unroll
      for (int rt = 0; rt < RT; ++rt)
        acc[rt][ct] = __builtin_amdgcn_mfma_f32_16x16x32_bf16(areg[rt][kk], b, acc[rt][ct], 0, 0, 0);
    }

  #pragma unroll
  for (int rt = 0; rt < RT; ++rt)
    #pragma unroll
    for (int ct = 0; ct < NCT; ++ct) {
      int col = ct * 16 + m15;
      #pragma unroll
      for (int r = 0; r < 4; ++r) {
        long row = bm + wv * (BM / 4) + rt * 16 + quad * 4 + r;
        float v = acc[rt][ct][r];
        if (ADD_RES) v += res[row * ldr + col];
        if (OUT_BF16) ((bf16*)outp)[row * ldo + col] = f2b(v);
        else          ((float*)outp)[row * ldo + col] = v;
      }
    }
}

// ======== qkv GEMM with fused LayerNorm on A, full 288-col output/block ========
__global__ __launch_bounds__(256, 2) void mfma_gemm_lnA(
    const float* __restrict__ X, const float* __restrict__ gam, const float* __restrict__ bet,
    const bf16* __restrict__ Wt,   // [288][96]
    bf16* __restrict__ outp)
{
  const int tid  = threadIdx.x;
  const long bm  = (long)blockIdx.x * 128;
  const int lane = tid & 63;
  const int wv   = tid >> 6;
  const int m15  = lane & 15;
  const int quad = lane >> 4;

  float xv[2][24];
  #pragma unroll
  for (int rt = 0; rt < 2; ++rt) {
    const float* xp = X + (bm + wv * 32 + rt * 16 + m15) * CDIM + quad * 8;
    #pragma unroll
    for (int kk = 0; kk < 3; ++kk) {
      float4 t0 = *reinterpret_cast<const float4*>(xp + kk * 32);
      float4 t1 = *reinterpret_cast<const float4*>(xp + kk * 32 + 4);
      xv[rt][kk * 8 + 0] = t0.x; xv[rt][kk * 8 + 1] = t0.y; xv[rt][kk * 8 + 2] = t0.z; xv[rt][kk * 8 + 3] = t0.w;
      xv[rt][kk * 8 + 4] = t1.x; xv[rt][kk * 8 + 5] = t1.y; xv[rt][kk * 8 + 6] = t1.z; xv[rt][kk * 8 + 7] = t1.w;
    }
  }
  float gv[24], bv[24];
  #pragma unroll
  for (int kk = 0; kk < 3; ++kk) {
    float4 g0 = *reinterpret_cast<const float4*>(gam + kk * 32 + quad * 8);
    float4 g1 = *reinterpret_cast<const float4*>(gam + kk * 32 + quad * 8 + 4);
    float4 b0 = *reinterpret_cast<const float4*>(bet + kk * 32 + quad * 8);
    float4 b1 = *reinterpret_cast<const float4*>(bet + kk * 32 + quad * 8 + 4);
    gv[kk * 8 + 0] = g0.x; gv[kk * 8 + 1] = g0.y; gv[kk * 8 + 2] = g0.z; gv[kk * 8 + 3] = g0.w;
    gv[kk * 8 + 4] = g1.x; gv[kk * 8 + 5] = g1.y; gv[kk * 8 + 6] = g1.z; gv[kk * 8 + 7] = g1.w;
    bv[kk * 8 + 0] = b0.x; bv[kk * 8 + 1] = b0.y; bv[kk * 8 + 2] = b0.z; bv[kk * 8 + 3] = b0.w;
    bv[kk * 8 + 4] = b1.x; bv[kk * 8 + 5] = b1.y; bv[kk * 8 + 6] = b1.z; bv[kk * 8 + 7] = b1.w;
  }

  short8 areg[2][3];
  #pragma unroll
  for (int rt = 0; rt < 2; ++rt) {
    float s = 0.f, sq = 0.f;
    #pragma unroll
    for (int e = 0; e < 24; ++e) { s += xv[rt][e]; sq += xv[rt][e] * xv[rt][e]; }
    s  += __shfl_xor(s, 16);  s  += __shfl_xor(s, 32);
    sq += __shfl_xor(sq, 16); sq += __shfl_xor(sq, 32);
    float mean = s * (1.f / 96.f);
    float var  = sq * (1.f / 96.f) - mean * mean;
    float rstd = rsqrtf(var + EPSV);
    #pragma unroll
    for (int kk = 0; kk < 3; ++kk)
      #pragma unroll
      for (int j = 0; j < 8; ++j)
        areg[rt][kk][j] = f2bs((xv[rt][kk * 8 + j] - mean) * rstd * gv[kk * 8 + j] + bv[kk * 8 + j]);
  }

  floatx4 acc[2][18];
  #pragma unroll
  for (int rt = 0; rt < 2; ++rt)
    #pragma unroll
    for (int ct = 0; ct < 18; ++ct)
      acc[rt][ct] = (floatx4){0.f, 0.f, 0.f, 0.f};

  const bf16* wp = Wt + m15 * 96 + quad * 8;
  #pragma unroll
  for (int kk = 0; kk < 3; ++kk)
    #pragma unroll
    for (int ct = 0; ct < 18; ++ct) {
      short8 b = *reinterpret_cast<const short8*>(wp + ct * 16 * 96 + kk * 32);
      #pragma unroll
      for (int rt = 0; rt < 2; ++rt)
        acc[rt][ct] = __builtin_amdgcn_mfma_f32_16x16x32_bf16(areg[rt][kk], b, acc[rt][ct], 0, 0, 0);
    }

  #pragma unroll
  for (int rt = 0; rt < 2; ++rt)
    #pragma unroll
    for (int ct = 0; ct < 18; ++ct) {
      int col = ct * 16 + m15;
      #pragma unroll
      for (int r = 0; r < 4; ++r) {
        long row = bm + wv * 32 + rt * 16 + quad * 4 + r;
        outp[row * C3 + col] = f2b(acc[rt][ct][r]);
      }
    }
}

// ======== attn-out GEMM (v @ M_b^T) + residual + fused LayerNorm2 epilogue ========
__global__ __launch_bounds__(256, 2) void mfma_gemm_attn(
    const bf16* __restrict__ A, const bf16* __restrict__ Mt,
    const float* __restrict__ res, const float* __restrict__ gam, const float* __restrict__ bet,
    float* __restrict__ outp, bf16* __restrict__ y2)
{
  const int tid  = threadIdx.x;
  const long bm  = (long)blockIdx.x * 128;
  const int lane = tid & 63;
  const int wv   = tid >> 6;
  const int m15  = lane & 15;
  const int quad = lane >> 4;

  short8 areg[2][3];
  #pragma unroll
  for (int rt = 0; rt < 2; ++rt) {
    const bf16* ap = A + (bm + wv * 32 + rt * 16 + m15) * C3 + quad * 8;
    #pragma unroll
    for (int kk = 0; kk < 3; ++kk)
      areg[rt][kk] = *reinterpret_cast<const short8*>(ap + kk * 32);
  }

  floatx4 acc[2][6];
  #pragma unroll
  for (int rt = 0; rt < 2; ++rt)
    #pragma unroll
    for (int ct = 0; ct < 6; ++ct)
      acc[rt][ct] = (floatx4){0.f, 0.f, 0.f, 0.f};

  const bf16* mp = Mt + (bm >> 16) * (CDIM * CDIM) + m15 * 96 + quad * 8;
  #pragma unroll
  for (int kk = 0; kk < 3; ++kk)
    #pragma unroll
    for (int ct = 0; ct < 6; ++ct) {
      short8 b = *reinterpret_cast<const short8*>(mp + ct * 16 * 96 + kk * 32);
      #pragma unroll
      for (int rt = 0; rt < 2; ++rt)
        acc[rt][ct] = __builtin_amdgcn_mfma_f32_16x16x32_bf16(areg[rt][kk], b, acc[rt][ct], 0, 0, 0);
    }

  float gv[6], bv[6];
  #pragma unroll
  for (int ct = 0; ct < 6; ++ct) { gv[ct] = gam[ct * 16 + m15]; bv[ct] = bet[ct * 16 + m15]; }

  #pragma unroll
  for (int rt = 0; rt < 2; ++rt)
    #pragma unroll
    for (int r = 0; r < 4; ++r) {
      long row = bm + wv * 32 + rt * 16 + quad * 4 + r;
      float v[6];
      float s = 0.f, sq = 0.f;
      #pragma unroll
      for (int ct = 0; ct < 6; ++ct) {
        v[ct] = acc[rt][ct][r] + res[row * CDIM + ct * 16 + m15];
        s += v[ct]; sq += v[ct] * v[ct];
      }
      #pragma unroll
      for (int off = 8; off; off >>= 1) { s += __shfl_xor(s, off); sq += __shfl_xor(sq, off); }
      float mean = s * (1.f / 96.f);
      float var  = sq * (1.f / 96.f) - mean * mean;
      float rstd = rsqrtf(var + EPSV);
      #pragma unroll
      for (int ct = 0; ct < 6; ++ct) {
        int col = ct * 16 + m15;
        outp[row * CDIM + col] = v[ct];
        y2[row * CDIM + col] = f2b((v[ct] - mean) * rstd * gv[ct] + bv[ct]);
      }
    }
}

// ======== Spatially-tiled depthwise 3x3 conv, vectorized 8-ch I/O ========
template<int LDC, int TC, int MODE>
__global__ __launch_bounds__(256) void dwconv_tiled(
    const bf16* __restrict__ in, const float* __restrict__ kw, int kws, int cmax,
    bf16* __restrict__ out, int ldo)
{
  constexpr int VPP = TC / 8;
  __shared__ uint4 sm[VPP][18 * 18];
  const int tid = threadIdx.x;
  const int tx0 = blockIdx.x * 16;
  const int ty0 = (blockIdx.y & 15) * 16;
  const int b   = blockIdx.y >> 4;
  const int c0  = blockIdx.z * TC;
  const long bbase = (long)b * HWSZ;

  for (int f = tid; f < 18 * 18 * VPP; f += 256) {
    int pix = f / VPP;
    int v   = f - pix * VPP;
    int row = pix / 18, px = pix - row * 18;
    int y = ty0 + row - 1, x = tx0 + px - 1;
    uint4 u = make_uint4(0u, 0u, 0u, 0u);
    if ((unsigned)y < (unsigned)HH && (unsigned)x < (unsigned)WW)
      u = *reinterpret_cast<const uint4*>(in + (bbase + (long)y * WW + x) * LDC + c0 + v * 8);
    sm[v][pix] = u;
  }
  __syncthreads();

  const int x   = tid & 15;
  const int yg  = (tid >> 4) & 3;
  const int chl = tid >> 6;
  for (int cg = chl; cg < VPP; cg += 4) {
    const int cb = c0 + cg * 8;
    float wgt[9][8];
    #pragma unroll
    for (int t = 0; t < 9; ++t)
      #pragma unroll
      for (int j = 0; j < 8; ++j)
        wgt[t][j] = (cb + j < cmax) ? kw[t * kws + cb + j] : 0.f;

    #pragma unroll
    for (int yy = 0; yy < 4; ++yy) {
      const int ry = yg * 4 + yy;
      float acc[8] = {0.f, 0.f, 0.f, 0.f, 0.f, 0.f, 0.f, 0.f};
      #pragma unroll
      for (int dy = 0; dy < 3; ++dy)
        #pragma unroll
        for (int dx = 0; dx < 3; ++dx) {
          uint4 u = sm[cg][(ry + dy) * 18 + x + dx];
          const float* wt = wgt[dy * 3 + dx];
          acc[0] += lo16(u.x) * wt[0]; acc[1] += hi16(u.x) * wt[1];
          acc[2] += lo16(u.y) * wt[2]; acc[3] += hi16(u.y) * wt[3];
          acc[4] += lo16(u.z) * wt[4]; acc[5] += hi16(u.z) * wt[5];
          acc[6] += lo16(u.w) * wt[6]; acc[7] += hi16(u.w) * wt[7];
        }
      long po = bbase + (long)(ty0 + yg * 4 + yy) * WW + tx0 + x;
      bf16* op = out + po * ldo + cb;
      __align__(16) bf16 ov[8];
      if (MODE == 0) {
        #pragma unroll
        for (int j = 0; j < 8; ++j) ov[j] = f2b(acc[j]);
      } else if (MODE == 1) {
        #pragma unroll
        for (int j = 0; j < 8; ++j)
          ov[j] = f2b(0.5f * acc[j] * (1.f + erff(acc[j] * 0.70710678118654752440f)));
      } else {
        uint4 old = *reinterpret_cast<const uint4*>(op);
        ov[0] = f2b(lo16(old.x) * acc[0]); ov[1] = f2b(hi16(old.x) * acc[1]);
        ov[2] = f2b(lo16(old.y) * acc[2]); ov[3] = f2b(hi16(old.y) * acc[3]);
        ov[4] = f2b(lo16(old.z) * acc[4]); ov[5] = f2b(hi16(old.z) * acc[5]);
        ov[6] = f2b(lo16(old.w) * acc[6]); ov[7] = f2b(hi16(old.w) * acc[7]);
      }
      *reinterpret_cast<uint4*>(op) = *reinterpret_cast<const uint4*>(ov);
    }
  }
}

// ======== MFMA Gram + fused q/k L2 norms — atomic-free, per-block partials ========
__global__ __launch_bounds__(256) void gram_kernel(const bf16* __restrict__ qkv,
    float* __restrict__ Gpart, float* __restrict__ Npart)
{
  constexpr int SP = 264;
  __shared__ __align__(16) char raw[2 * CH * SP * 2];   // 50688 B
  short* qs = (short*)raw;              // [48][SP]
  short* ks = qs + CH * SP;
  const int tid  = threadIdx.x;
  const int bh   = blockIdx.y;
  const int b    = bh >> 1, head = bh & 1;
  const long row0 = (long)b * HWSZ + (long)blockIdx.x * 256;
  const int lane = tid & 63;
  const int wv   = tid >> 6;
  const int m15  = lane & 15;
  const int quad = lane >> 4;

  {
    const short* src = (const short*)(qkv + (row0 + tid) * C3 + head * CH);
    #pragma unroll
    for (int v = 0; v < 6; ++v) {
      short8 q8 = *reinterpret_cast<const short8*>(src + v * 8);
      short8 k8 = *reinterpret_cast<const short8*>(src + CDIM + v * 8);
      #pragma unroll
      for (int j = 0; j < 8; ++j) {
        qs[(v * 8 + j) * SP + tid] = q8[j];
        ks[(v * 8 + j) * SP + tid] = k8[j];
      }
    }
  }
  __syncthreads();

  floatx4 acc[3][3], accq[3], acck[3];
  #pragma unroll
  for (int i = 0; i < 3; ++i) {
    accq[i] = (floatx4){0.f, 0.f, 0.f, 0.f};
    acck[i] = (floatx4){0.f, 0.f, 0.f, 0.f};
    #pragma unroll
    for (int j = 0; j < 3; ++j) acc[i][j] = (floatx4){0.f, 0.f, 0.f, 0.f};
  }

  #pragma unroll
  for (int kk = 0; kk < 2; ++kk) {
    const int s_off = wv * 64 + kk * 32 + quad * 8;
    short8 aq[3], bk[3];
    #pragma unroll
    for (int i = 0; i < 3; ++i) {
      aq[i] = *reinterpret_cast<const short8*>(&qs[(i * 16 + m15) * SP + s_off]);
      bk[i] = *reinterpret_cast<const short8*>(&ks[(i * 16 + m15) * SP + s_off]);
    }
    #pragma unroll
    for (int i = 0; i < 3; ++i) {
      accq[i] = __builtin_amdgcn_mfma_f32_16x16x32_bf16(aq[i], aq[i], accq[i], 0, 0, 0);
      acck[i] = __builtin_amdgcn_mfma_f32_16x16x32_bf16(bk[i], bk[i], acck[i], 0, 0, 0);
      #pragma unroll
      for (int j = 0; j < 3; ++j)
        acc[i][j] = __builtin_amdgcn_mfma_f32_16x16x32_bf16(aq[i], bk[j], acc[i][j], 0, 0, 0);
    }
  }

  __syncthreads();
  // per-wave partials in LDS (stride 49 rows -> bank-conflict-free), no atomics
  float* part  = (float*)raw;            // [4][48*49] = 9408 floats
  float* npart = part + 4 * 48 * 49;     // [4][96]
  const int c_lo = quad * 4;
  #pragma unroll
  for (int i = 0; i < 3; ++i)
    #pragma unroll
    for (int j = 0; j < 3; ++j)
      #pragma unroll
      for (int r = 0; r < 4; ++r)
        part[wv * 2352 + (i * 16 + c_lo + r) * 49 + j * 16 + m15] = acc[i][j][r];
  if (m15 >= c_lo && m15 < c_lo + 4) {
    const int r = m15 - c_lo;
    #pragma unroll
    for (int i = 0; i < 3; ++i) {
      npart[wv * 96 + i * 16 + m15]      = accq[i][r];
      npart[wv * 96 + 48 + i * 16 + m15] = acck[i][r];
    }
  }
  __syncthreads();
  // block partial = sum of 4 wave partials; coalesced non-atomic store
  float* Gp = Gpart + ((long)blockIdx.x * 4 + bh) * 2304;
  for (int f = tid; f < 2304; f += 256) {
    int row = f / 48, col = f - row * 48;
    int o = row * 49 + col;
    Gp[f] = part[o] + part[2352 + o] + part[4704 + o] + part[7056 + o];
  }
  if (tid < 96)
    Npart[((long)blockIdx.x * 4 + bh) * 96 + tid] =
        npart[tid] + npart[96 + tid] + npart[192 + tid] + npart[288 + tid];
}

// ---- sum the 256 chunk partials per bh into G / nq / nk ----
__global__ __launch_bounds__(256) void gram_reduce(const float* __restrict__ Gpart,
    const float* __restrict__ Npart, float* __restrict__ G,
    float* __restrict__ nq, float* __restrict__ nk)
{
  const int bh = blockIdx.x;
  const int b = bh >> 1, head = bh & 1;
  if (blockIdx.y < 9) {
    const int f = blockIdx.y * 256 + threadIdx.x;
    float s = 0.f;
    #pragma unroll 8
    for (int c = 0; c < 256; ++c) s += Gpart[((long)c * 4 + bh) * 2304 + f];
    G[(long)bh * 2304 + f] = s;
  } else {
    const int t = threadIdx.x;
    if (t < 96) {
      float s = 0.f;
      #pragma unroll 8
      for (int c = 0; c < 256; ++c) s += Npart[((long)c * 4 + bh) * 96 + t];
      if (t < 48) nq[b * CDIM + head * CH + t] = s;
      else        nk[b * CDIM + head * CH + t - 48] = s;
    }
  }
}

// ---------------- softmax over d of G/(|q||k|)*temp ----------------
__global__ __launch_bounds__(64) void softmax_kernel(const float* __restrict__ G,
    const float* __restrict__ nq, const float* __restrict__ nk,
    const float* __restrict__ temp, float* __restrict__ attn)
{
  int r = blockIdx.x;               // 0..191 = (b*2+head)*48 + c
  int lane = threadIdx.x;
  int bh = r / CH, c = r % CH;
  int b = bh >> 1, head = bh & 1;
  float t  = temp[head];
  float qn = sqrtf(nq[b * CDIM + head * CH + c]);
  float val = 0.f, v = -INFINITY;
  if (lane < CH) {
    float kn = sqrtf(nk[b * CDIM + head * CH + lane]);
    val = G[r * CH + lane] / (qn * kn) * t;
    v = val;
  }
  float m = v;
  #pragma unroll
  for (int off = 32; off; off >>= 1) m = fmaxf(m, __shfl_xor(m, off));
  float e = (lane < CH) ? expf(val - m) : 0.f;
  float s = e;
  #pragma unroll
  for (int off = 32; off; off >>= 1) s += __shfl_xor(s, off);
  if (lane < CH) attn[r * CH + lane] = e / s;
}

// ---- Mt[b][n][k] (bf16) = sum_cc attn[b,head(k)][cc][k%48] * aow[head(k)*48+cc][n] ----
__global__ __launch_bounds__(256) void attnmat_kernel(const float* __restrict__ attn,
    const float* __restrict__ aow, bf16* __restrict__ Mt)
{
  const int b  = blockIdx.x;
  const int k0 = blockIdx.y * 16;
  for (int idx = threadIdx.x; idx < 16 * 96; idx += 256) {
    int k = k0 + idx / 96, n = idx % 96;
    int h = k / CH, kk = k % CH;
    const float* ap = attn + ((b * 2 + h) * CH) * CH + kk;  // attn[bh][cc][kk], stride CH
    const float* wp = aow + (h * CH) * CDIM + n;            // aow[h*48+cc][n], stride CDIM
    float acc = 0.f;
    #pragma unroll
    for (int cc = 0; cc < CH; ++cc) acc += ap[cc * CH] * wp[cc * CDIM];
    Mt[(long)b * CDIM * CDIM + n * CDIM + k] = f2b(acc);    // transposed, k-major
  }
}

extern "C" void kernel_launch(void* const* d_in, const int* in_sizes, int n_in,
                              void* d_out, int out_size, void* d_ws, size_t ws_size,
                              hipStream_t stream)
{
  const float* x          = (const float*)d_in[0];
  const float* ln1_g      = (const float*)d_in[1];
  const float* ln1_b      = (const float*)d_in[2];
  const float* ln2_g      = (const float*)d_in[3];
  const float* ln2_b      = (const float*)d_in[4];
  const float* qkv_w      = (const float*)d_in[5];
  const float* qkv_dw     = (const float*)d_in[6];
  const float* temp       = (const float*)d_in[7];
  const float* attn_out_w = (const float*)d_in[8];
  const float* ffn_in_w   = (const float*)d_in[9];
  const float* ffn_dw     = (const float*)d_in[10];
  const float* ffn_out_w  = (const float*)d_in[11];
  float* out = (float*)d_out;

  // workspace layout (peak ~177 MB)
  char* ws = (char*)d_ws;
  size_t off = 0;
  auto alloc = [&](size_t bytes) { void* p = ws + off; off += (bytes + 255) & ~(size_t)255; return p; };
  bf16*  BA  = (bf16*)alloc((size_t)NPIX * C3 * 2);    // qkv post-dwconv; later gelu(x1)/gated
  bf16*  BB  = (bf16*)alloc((size_t)NPIX * C3 * 2);    // qkv pre-dwconv; later t1/t2; gram partials
  bf16*  BC  = (bf16*)alloc((size_t)NPIX * CDIM * 2);  // LN2 output (from attn epilogue)
  float* NQ  = (float*)alloc(BATCH * CDIM * 4);
  float* NK  = (float*)alloc(BATCH * CDIM * 4);
  float* G   = (float*)alloc(BATCH * HEADS * CH * CH * 4);
  float* ATT = (float*)alloc(BATCH * HEADS * CH * CH * 4);
  bf16*  MT  = (bf16*)alloc((size_t)BATCH * CDIM * CDIM * 2); // fused attn matrices, k-major bf16
  bf16*  WQ  = (bf16*)alloc(288 * 96 * 2);
  bf16*  WF1 = (bf16*)alloc(256 * 96 * 2);
  bf16*  WF2 = (bf16*)alloc(256 * 96 * 2);
  bf16*  WO  = (bf16*)alloc(96 * 256 * 2);

  // gram partials alias the (dead at that point) BB buffer: 256*4*(2304+96) floats = 9.8 MB
  float* GP = (float*)BB;
  float* NP = GP + (size_t)256 * 4 * 2304;

  // one-shot weight transposes (k-major bf16)
  prep_wt<<<396, 256, 0, stream>>>(qkv_w, ffn_in_w, ffn_out_w, WQ, WF1, WF2, WO);

  // ---- attention branch ----
  // qkv = dwconv(LN1(x) @ qkv_w)
  mfma_gemm_lnA<<<NPIX / 128, 256, 0, stream>>>(x, ln1_g, ln1_b, WQ, BB);
  dwconv_tiled<C3, 48, 0><<<dim3(16, 32, 6), 256, 0, stream>>>(BB, qkv_dw, C3, C3, BA, C3);
  gram_kernel<<<dim3(256, 4), 256, 0, stream>>>(BA, GP, NP);
  gram_reduce<<<dim3(4, 10), 256, 0, stream>>>(GP, NP, G, NQ, NK);
  softmax_kernel<<<192, 64, 0, stream>>>(G, NQ, NK, temp, ATT);
  attnmat_kernel<<<dim3(2, 6), 256, 0, stream>>>(ATT, attn_out_w, MT);
  // out = x + v @ M_b;  BC = LN2(out)
  mfma_gemm_attn<<<NPIX / 128, 256, 0, stream>>>(
      BA + 2 * CDIM, MT, x, ln2_g, ln2_b, out, BC);

  // ---- FFN branch (hidden split into two 255-col halves; col 255 pads as zeros) ----
  mfma_gemm<128, 256, 96, false, true><<<NPIX / 128, 256, 0, stream>>>(
      BC, CDIM, WF1, BB, 256, nullptr, 0);
  dwconv_tiled<256, 64, 1><<<dim3(16, 32, 4), 256, 0, stream>>>(BB, ffn_dw, 2 * HIDN, HIDN, BA, 256);
  mfma_gemm<128, 256, 96, false, true><<<NPIX / 128, 256, 0, stream>>>(
      BC, CDIM, WF2, BB, 256, nullptr, 0);
  dwconv_tiled<256, 64, 2><<<dim3(16, 32, 4), 256, 0, stream>>>(BB, ffn_dw + HIDN, 2 * HIDN, HIDN, BA, 256);
  mfma_gemm<128, 96, 256, true, false><<<NPIX / 128, 256, 0, stream>>>(
      BA, 256, WO, out, CDIM, out, CDIM);
}